// Round 1
// baseline (308.556 us; speedup 1.0000x reference)
//
#include <hip/hip_runtime.h>
#include <cstdint>

#define C_    512
#define HW_   784
#define B_    64
#define BN_EPS 1e-5f

// Workspace layout:
//   [0, 32768)        : wbits   uint32[512][16]   (bit c%32 of word c/32 = 1 iff W[o][c] < 0)
//   [32768, 40960)    : params  float4[512]       {A2, C2, slope, bias}
//
// Math folding:
//   scale[o] = mean|W[o,:]| ; S = 512 - 2*P (P = popcount(a^wsign)) ; y = scale*S
//   bn = A*S + B2,  A = gamma*scale*r, B2 = beta - gamma*mean*r
//   t  = bn + x - shift = (-2A)*P + (512A + B2 - shift) + x = A2*P + C2 + x
//   out = max(t,0) + slope*min(t,0) + bias   (branchless RPReLU)

__global__ __launch_bounds__(64) void precompute_kernel(
    const float* __restrict__ W,
    const float* __restrict__ bn_gamma, const float* __restrict__ bn_beta,
    const float* __restrict__ bn_mean,  const float* __restrict__ bn_var,
    const float* __restrict__ pr_slope, const float* __restrict__ pr_shift,
    const float* __restrict__ pr_bias,
    uint32_t* __restrict__ wbits, float4* __restrict__ params)
{
    const int o    = blockIdx.x;
    const int lane = threadIdx.x;
    const float* wrow = W + (size_t)o * C_;

    // mean(|W[o,:]|): stride-64 partials + wave-64 butterfly
    float s = 0.f;
    for (int c = lane; c < C_; c += 64) s += fabsf(wrow[c]);
    for (int off = 32; off > 0; off >>= 1) s += __shfl_down(s, off, 64);

    // sign bits: lanes 0..15 each pack one 32-bit word
    if (lane < 16) {
        uint32_t m = 0;
        const int cbase = lane * 32;
        #pragma unroll
        for (int t = 0; t < 32; ++t) {
            if (wrow[cbase + t] < 0.f) m |= (1u << t);
        }
        wbits[o * 16 + lane] = m;
    }

    if (lane == 0) {
        float scale = s * (1.0f / (float)C_);
        float r  = rsqrtf(bn_var[o] + BN_EPS);
        float A  = bn_gamma[o] * scale * r;
        float A2 = -2.0f * A;
        float C2 = (float)C_ * A + bn_beta[o] - bn_gamma[o] * bn_mean[o] * r
                 - pr_shift[o];
        params[o] = make_float4(A2, C2, pr_slope[o], pr_bias[o]);
    }
}

// Block: (64 lanes) x (8 waves) = 512 threads. Grid: 784 blocks covering the
// 50,176 flattened (b,hw) pairs EXACTLY (50176 = 784*64) -> no invalid lanes,
// no 16/64-lane tail tile. 784 blocks * 512 thr = 401K threads, 4 blocks/CU
// resident (2048-thread cap) -> the ENTIRE grid is co-resident in one round
// (vs 1.625 rounds before; measured occupancy 63% was that second-round tail).
// Wave jj binarizes channels [64jj, 64jj+64) (2 bit-words) and computes the
// same 64 output channels (so its phase-2 residual x re-reads are the exact
// addresses it touched in phase 1 -> L1/L2 hot).
// __launch_bounds__(512,8): 8 waves/SIMD -> VGPR cap 64; explicit register
// batches (v[16], xv[8]) force deep load pipelining the old 24-VGPR codegen
// never had.
__global__ __launch_bounds__(512, 8) void fused_kernel(
    const float* __restrict__ x, const float* __restrict__ rsign_bias,
    const uint32_t* __restrict__ wbits, const float4* __restrict__ params,
    float* __restrict__ out)
{
    // a-bit tile: 64 pair-rows x 16 words, stride 17 -> 2-way bank alias (free)
    __shared__ uint32_t abits[64 * 17];

    const int i  = threadIdx.x;                                   // pair lane (0..63)
    const int jj = __builtin_amdgcn_readfirstlane(threadIdx.y);   // wave-uniform (0..7)

    const uint32_t pair = (uint32_t)blockIdx.x * 64u + (uint32_t)i;
    const uint32_t b    = pair / 784u;          // magic-mul division
    const uint32_t hw   = pair - b * 784u;
    const size_t   base = (size_t)b * (C_ * HW_) + hw;
    const float*   xg   = x + base;

    const int c0 = jj * 64;                                       // wave-uniform

    // ---- Phase 1: binarize channels [c0, c0+64) -> two bit-words ----
    uint32_t m0 = 0, m1 = 0;
    #pragma unroll
    for (int half = 0; half < 4; ++half) {
        float v[16];                     // explicit batch: 16 loads in flight
        #pragma unroll
        for (int t = 0; t < 16; ++t)
            v[t] = xg[(size_t)(c0 + half * 16 + t) * HW_];
        #pragma unroll
        for (int t = 0; t < 16; ++t) {
            const int c = half * 16 + t;                 // 0..63, compile-time
            const float s = v[t] + rsign_bias[c0 + c];   // bias via s_load
            if (c < 32) { if (s < 0.f) m0 |= (1u << c); }
            else        { if (s < 0.f) m1 |= (1u << (c - 32)); }
        }
    }
    abits[i * 17 + 2 * jj]     = m0;
    abits[i * 17 + 2 * jj + 1] = m1;
    __syncthreads();

    // ---- Phase 2: full 512-bit activation row from LDS (4x ds_read_b128) ----
    uint32_t a[16];
    #pragma unroll
    for (int w = 0; w < 16; ++w) a[w] = abits[i * 17 + w];

    float* og = out + base;

    #pragma unroll
    for (int chunk = 0; chunk < 8; ++chunk) {
        float xv[8];                      // prefetch residual x for 8 outputs
        #pragma unroll
        for (int u = 0; u < 8; ++u)
            xv[u] = xg[(size_t)(c0 + chunk * 8 + u) * HW_];
        #pragma unroll
        for (int u = 0; u < 8; ++u) {
            const int o = c0 + chunk * 8 + u;            // wave-uniform
            const uint32_t* wr = wbits + o * 16;         // s_load rows
            int P = 0;
            #pragma unroll
            for (int w = 0; w < 16; ++w) P += __popc(a[w] ^ wr[w]);

            const float4 p = params[o];
            const float t = fmaf(p.x, (float)P, p.y + xv[u]);
            const float r = fmaf(p.z, fminf(t, 0.f), fmaxf(t, 0.f) + p.w);
            // out is never re-read: nontemporal store keeps 100 MB of writes
            // from evicting the x tile phase 2 is re-reading from L2/L3.
            __builtin_nontemporal_store(r, &og[(size_t)o * HW_]);
        }
    }
}

extern "C" void kernel_launch(void* const* d_in, const int* in_sizes, int n_in,
                              void* d_out, int out_size, void* d_ws, size_t ws_size,
                              hipStream_t stream) {
    const float* x          = (const float*)d_in[0];
    const float* rsign_bias = (const float*)d_in[1];
    const float* W          = (const float*)d_in[2];
    const float* bn_gamma   = (const float*)d_in[3];
    const float* bn_beta    = (const float*)d_in[4];
    const float* bn_mean    = (const float*)d_in[5];
    const float* bn_var     = (const float*)d_in[6];
    const float* pr_slope   = (const float*)d_in[7];
    const float* pr_shift   = (const float*)d_in[8];
    const float* pr_bias    = (const float*)d_in[9];
    float* out = (float*)d_out;

    uint32_t* wbits  = (uint32_t*)d_ws;
    float4*   params = (float4*)((char*)d_ws + 32768);

    precompute_kernel<<<dim3(C_), dim3(64), 0, stream>>>(
        W, bn_gamma, bn_beta, bn_mean, bn_var, pr_slope, pr_shift, pr_bias,
        wbits, params);

    // 50176 (b,hw) pairs = 784 tiles of 64, zero waste; 512-thr blocks,
    // whole grid co-resident (4 blocks/CU).
    fused_kernel<<<dim3(784), dim3(64, 8), 0, stream>>>(
        x, rsign_bias, wbits, params, out);
}

// Round 2
// 230.926 us; speedup vs baseline: 1.3362x; 1.3362x over previous
//
#include <hip/hip_runtime.h>
#include <cstdint>

#define C_    512
#define HW_   784
#define B_    64
#define BN_EPS 1e-5f

// Workspace layout:
//   [0, 32768)        : wbits   uint32[512][16]   (bit c%32 of word c/32 = 1 iff W[o][c] < 0)
//   [32768, 40960)    : params  float4[512]       {A2, C2, slope, bias}
//
// Math folding:
//   scale[o] = mean|W[o,:]| ; S = 512 - 2*P (P = popcount(a^wsign)) ; y = scale*S
//   bn = A*S + B2,  A = gamma*scale*r, B2 = beta - gamma*mean*r
//   t  = bn + x - shift = (-2A)*P + (512A + B2 - shift) + x = A2*P + C2 + x
//   out = max(t,0) + slope*min(t,0) + bias   (branchless RPReLU)
//
// R1 post-mortem (do not revisit):
//   - nontemporal output stores: WRITE_SIZE 100->238 MB (no-allocate write
//     amplification) AND evicted x from L3 so phase-2 re-reads all missed
//     (FETCH 127->196 MB). 2x regression. Plain stores only.
//   - This round instead removes the phase-2 x re-read entirely (register
//     cache), which was the actual latency bottleneck in R0.

__global__ __launch_bounds__(64) void precompute_kernel(
    const float* __restrict__ W,
    const float* __restrict__ bn_gamma, const float* __restrict__ bn_beta,
    const float* __restrict__ bn_mean,  const float* __restrict__ bn_var,
    const float* __restrict__ pr_slope, const float* __restrict__ pr_shift,
    const float* __restrict__ pr_bias,
    uint32_t* __restrict__ wbits, float4* __restrict__ params)
{
    const int o    = blockIdx.x;
    const int lane = threadIdx.x;
    const float* wrow = W + (size_t)o * C_;

    // mean(|W[o,:]|): stride-64 partials + wave-64 butterfly
    float s = 0.f;
    for (int c = lane; c < C_; c += 64) s += fabsf(wrow[c]);
    for (int off = 32; off > 0; off >>= 1) s += __shfl_down(s, off, 64);

    // sign bits: lanes 0..15 each pack one 32-bit word
    if (lane < 16) {
        uint32_t m = 0;
        const int cbase = lane * 32;
        #pragma unroll
        for (int t = 0; t < 32; ++t) {
            if (wrow[cbase + t] < 0.f) m |= (1u << t);
        }
        wbits[o * 16 + lane] = m;
    }

    if (lane == 0) {
        float scale = s * (1.0f / (float)C_);
        float r  = rsqrtf(bn_var[o] + BN_EPS);
        float A  = bn_gamma[o] * scale * r;
        float A2 = -2.0f * A;
        float C2 = (float)C_ * A + bn_beta[o] - bn_gamma[o] * bn_mean[o] * r
                 - pr_shift[o];
        params[o] = make_float4(A2, C2, pr_slope[o], pr_bias[o]);
    }
}

// Block: (64 lanes) x (16 waves) = 1024 threads; grid = 784 blocks covering
// the 50,176 flattened (b,hw) pairs exactly (784*64), zero invalid lanes.
// Wave jj binarizes channels [32jj, 32jj+32) for its 64 pairs AND computes
// outputs for those same channels. The residual x values phase 2 needs are
// EXACTLY the values phase 1 loaded -> cache them in registers (xv[32])
// across the barrier. Phase 2 then touches global memory only for stores.
// VGPR budget: R0's code was 24 VGPRs; +32 x-cache ~= 56 <= 64, so
// __launch_bounds__(1024, 8) (8 waves/SIMD = 2 blocks/CU) holds.
__global__ __launch_bounds__(1024, 8) void fused_kernel(
    const float* __restrict__ x, const float* __restrict__ rsign_bias,
    const uint32_t* __restrict__ wbits, const float4* __restrict__ params,
    float* __restrict__ out)
{
    // a-bit tile: 64 pair-rows x 16 words, stride 17 -> 2-way bank alias (free)
    __shared__ uint32_t abits[64 * 17];

    const int i  = threadIdx.x;                                   // pair lane (0..63)
    const int jj = __builtin_amdgcn_readfirstlane(threadIdx.y);   // wave-uniform (0..15)

    const uint32_t pair = (uint32_t)blockIdx.x * 64u + (uint32_t)i;
    const uint32_t b    = pair / 784u;          // magic-mul division
    const uint32_t hw   = pair - b * 784u;
    const size_t   base = (size_t)b * (C_ * HW_) + hw;
    const float*   xg   = x + base;

    const int c0 = jj * 32;                                       // wave-uniform

    // ---- Phase 1: load this wave's 32 channels ONCE, keep in registers ----
    // 32 independent loads issued back-to-back: deep MLP for the compulsory
    // HBM read (R0's 24-VGPR codegen could only keep ~8 in flight).
    float xv[32];
    #pragma unroll
    for (int t = 0; t < 32; ++t)
        xv[t] = xg[(size_t)(c0 + t) * HW_];

    uint32_t m = 0;
    #pragma unroll
    for (int t = 0; t < 32; ++t) {
        if (xv[t] + rsign_bias[c0 + t] < 0.f) m |= (1u << t);   // bias: s_load
    }
    abits[i * 17 + jj] = m;
    __syncthreads();

    // ---- Phase 2: full 512-bit activation row from LDS; x from registers ----
    uint32_t a[16];
    #pragma unroll
    for (int w = 0; w < 16; ++w) a[w] = abits[i * 17 + w];

    float* og = out + base;

    #pragma unroll
    for (int oo = 0; oo < 32; ++oo) {
        const int o = c0 + oo;                           // wave-uniform
        const uint32_t* wr = wbits + o * 16;             // s_load rows (L2-hot)
        int P = 0;
        #pragma unroll
        for (int w = 0; w < 16; ++w) P += __popc(a[w] ^ wr[w]);

        const float4 p = params[o];
        const float t = fmaf(p.x, (float)P, p.y + xv[oo]);
        const float r = fmaf(p.z, fminf(t, 0.f), fmaxf(t, 0.f) + p.w);
        og[(size_t)o * HW_] = r;                         // plain store (see R1 note)
    }
}

extern "C" void kernel_launch(void* const* d_in, const int* in_sizes, int n_in,
                              void* d_out, int out_size, void* d_ws, size_t ws_size,
                              hipStream_t stream) {
    const float* x          = (const float*)d_in[0];
    const float* rsign_bias = (const float*)d_in[1];
    const float* W          = (const float*)d_in[2];
    const float* bn_gamma   = (const float*)d_in[3];
    const float* bn_beta    = (const float*)d_in[4];
    const float* bn_mean    = (const float*)d_in[5];
    const float* bn_var     = (const float*)d_in[6];
    const float* pr_slope   = (const float*)d_in[7];
    const float* pr_shift   = (const float*)d_in[8];
    const float* pr_bias    = (const float*)d_in[9];
    float* out = (float*)d_out;

    uint32_t* wbits  = (uint32_t*)d_ws;
    float4*   params = (float4*)((char*)d_ws + 32768);

    precompute_kernel<<<dim3(C_), dim3(64), 0, stream>>>(
        W, bn_gamma, bn_beta, bn_mean, bn_var, pr_slope, pr_shift, pr_bias,
        wbits, params);

    // 50176 (b,hw) pairs = 784 tiles of 64, zero waste; 1024-thr blocks,
    // 2 blocks/CU.
    fused_kernel<<<dim3(784), dim3(64, 16), 0, stream>>>(
        x, rsign_bias, wbits, params, out);
}